// Round 3
// baseline (414.635 us; speedup 1.0000x reference)
//
#include <hip/hip_runtime.h>
#include <math.h>

// TemporalSNNClassifier — bit-exact float32 emulation (proven round 2,
// absmax 0.0), restructured for wave balance.
//
// Round-2 failure mode: phase b ran on 4 of 8 waves -> VALUBusy 24%,
// dur 352us. Fix: class = wave-id (8 waves = 8 classes), row = lane
// (64 rows/block); EVERY thread does phase a (16 h) + one phase-b chain.
// W2[class][*] is wave-uniform -> preloaded into 128 VGPRs (occupancy is
// thread-count-limited at 2 waves/SIMD, so VGPRs up to 256 are free).
// Spike masks cross waves via double-buffered LDS -> 1 barrier/timestep.
//
// FROZEN numerics (do not touch): k-ascending single-accumulator fmaf
// chains for both GEMMs, bias as one separate add, leaky update
// ((0.9f*mem)+cur)-reset with contraction off, spike = (mem-1.0f > 0),
// reset_t == spk_{t-1}.

#define T_STEPS 64
#define IN_DIM  256
#define HID     128
#define NCLS    8
#define RPB     64    // rows per block
#define NTHR    512   // 8 waves

__global__ __launch_bounds__(NTHR, 2)
void snn_fp32(const float* __restrict__ x, const float* __restrict__ W1,
              const float* __restrict__ b1, const float* __restrict__ W2,
              const float* __restrict__ b2, float* __restrict__ out)
{
#pragma clang fp contract(off)
    __shared__ unsigned short smask[2][RPB * 8];   // [buf][row][q], 16 bits ea

    const int tid = threadIdx.x;
    const int r   = tid >> 3;            // phase-a row (0..63)
    const int q   = tid & 7;             // phase-a h-block (16 contiguous h)
    const int row = blockIdx.x * RPB + r;

    // phase-b identity: class = wave id (uniform), row = lane
    const int wcls = __builtin_amdgcn_readfirstlane(tid >> 6);
    const int ln   = tid & 63;

    // ---- cur1[h] = fmaf-chain_k( x[row,k]*W1[h,k] ) + b1[h], h=q*16+i ----
    float cur1[16];
    #pragma unroll
    for (int i = 0; i < 16; ++i) cur1[i] = 0.0f;

    const float* xrow = x + (size_t)row * IN_DIM;
    const float* w1b  = W1 + (size_t)(q * 16) * IN_DIM;
    for (int k = 0; k < IN_DIM; k += 4) {
        const float4 xv = *(const float4*)(xrow + k);
        #pragma unroll
        for (int i = 0; i < 16; ++i) {
            const float4 wv = *(const float4*)(w1b + i * IN_DIM + k);
            float c = cur1[i];
            c = fmaf(xv.x, wv.x, c);     // k ascending, single accumulator
            c = fmaf(xv.y, wv.y, c);
            c = fmaf(xv.z, wv.z, c);
            c = fmaf(xv.w, wv.w, c);
            cur1[i] = c;
        }
    }
    #pragma unroll
    for (int i = 0; i < 16; ++i)
        cur1[i] = cur1[i] + b1[q * 16 + i];

    // ---- preload W2[wcls][*] into VGPRs + b2 (wave-uniform class) ----
    float w2r[HID];
    {
        const float* src = W2 + (size_t)wcls * HID;
        #pragma unroll
        for (int i = 0; i < HID / 4; ++i) {
            const float4 v = *(const float4*)(src + 4 * i);
            w2r[4 * i + 0] = v.x; w2r[4 * i + 1] = v.y;
            w2r[4 * i + 2] = v.z; w2r[4 * i + 3] = v.w;
        }
    }
    const float b2c = b2[wcls];

    // ---- temporal loop ----
    float mem1[16], spk1[16];
    #pragma unroll
    for (int i = 0; i < 16; ++i) { mem1[i] = 0.0f; spk1[i] = 0.0f; }
    float m2 = 0.0f, r2 = 0.0f, o = 0.0f;

    __syncthreads();   // smask region ready for use

    for (int t = 0; t < T_STEPS; ++t) {
        // phase a: layer-1 leaky update for this thread's 16 h
        unsigned int mk = 0;
        #pragma unroll
        for (int i = 0; i < 16; ++i) {
            float tmp = 0.9f * mem1[i];   // rounded mul
            tmp = tmp + cur1[i];          // rounded add
            float m = tmp - spk1[i];      // rounded sub
            mem1[i] = m;
            const bool fire = ((m - 1.0f) > 0.0f);
            spk1[i] = fire ? 1.0f : 0.0f;
            mk |= fire ? (1u << i) : 0u;
        }
        smask[t & 1][r * 8 + q] = (unsigned short)mk;
        __syncthreads();
        // double buffer: next t writes smask[1-(t&1)], which cannot collide
        // with stragglers still reading smask[t&1] -> one barrier suffices.

        // phase b: class = wcls, row = ln; h-ascending 128-step fmaf chain
        const uint4 mv = *(const uint4*)&smask[t & 1][ln * 8];
        const unsigned int mw[4] = {mv.x, mv.y, mv.z, mv.w};
        float a = 0.0f;
        #pragma unroll
        for (int j = 0; j < 4; ++j) {
            const unsigned int m = mw[j];
            #pragma unroll
            for (int b = 0; b < 32; ++b) {
                const float s = (float)((m >> b) & 1u);
                a = fmaf(s, w2r[j * 32 + b], a);
            }
        }
        const float c2 = a + b2c;
        float t2 = 0.9f * m2; t2 = t2 + c2; m2 = t2 - r2;
        r2 = ((m2 - 1.0f) > 0.0f) ? 1.0f : 0.0f;
        o  = o + r2;
    }

    out[(size_t)(blockIdx.x * RPB + ln) * NCLS + wcls] = o;
}

extern "C" void kernel_launch(void* const* d_in, const int* in_sizes, int n_in,
                              void* d_out, int out_size, void* d_ws, size_t ws_size,
                              hipStream_t stream) {
    const float* x  = (const float*)d_in[0];
    const float* W1 = (const float*)d_in[1];
    const float* b1 = (const float*)d_in[2];
    const float* W2 = (const float*)d_in[3];
    const float* b2 = (const float*)d_in[4];
    float* out = (float*)d_out;

    const int batch = in_sizes[0] / IN_DIM;   // 16384
    const int grid  = batch / RPB;            // 256 blocks
    snn_fp32<<<grid, NTHR, 0, stream>>>(x, W1, b1, W2, b2, out);
}

// Round 4
// 407.731 us; speedup vs baseline: 1.0169x; 1.0169x over previous
//
#include <hip/hip_runtime.h>
#include <math.h>

// TemporalSNNClassifier — bit-exact fp32 emulation (absmax 0.0 since r2).
//
// r3 failure: w2r[128] never reached VGPRs (VGPR_Count=52) -> spill ops in
// the 128-step chain; VALU-busy cycles +64% vs r2, dur flat.
// r4: W2 lives in LDS (DS pipe co-issues with VALU); chain step is a
// masked add (bfe_i32 sign-extend -> and -> add), bit-identical to
// fmaf(s,w,a) for s in {0,1}; 256-thread blocks x2/CU hide barrier stalls.
//
// FROZEN numerics: k-ascending single-accumulator chains for both GEMMs
// (h ascending 0..127 in layer 2), bias as one separate add, leaky update
// ((0.9f*mem)+cur)-reset with contraction off, spike <=> mem > 1.0f,
// reset_t == spk_{t-1}.

#define T_STEPS 64
#define IN_DIM  256
#define HID     128
#define NCLS    8
#define RPB     32    // rows per block
#define NTHR    256   // 4 waves

// masked add term: bit b of m set -> w, else +0.0f. Bit-exact vs fmaf(s,w,.).
__device__ __forceinline__ float mand(unsigned int m, int b, float w) {
#if __has_builtin(__builtin_amdgcn_sbfe)
    int sel = __builtin_amdgcn_sbfe((int)m, b, 1);     // v_bfe_i32: 0 / -1
#else
    int sel = ((int)(m << (31 - b))) >> 31;
#endif
    return __int_as_float(sel & __float_as_int(w));
}

__global__ __launch_bounds__(NTHR, 2)
void snn_fp32(const float* __restrict__ x, const float* __restrict__ W1,
              const float* __restrict__ b1, const float* __restrict__ W2,
              const float* __restrict__ b2, float* __restrict__ out)
{
#pragma clang fp contract(off)
    __shared__ unsigned short smask[2][RPB * 8];   // [buf][row*8+q]
    __shared__ float w2s[NCLS][HID + 4];           // stride 132: class rows on
                                                   // different banks per half-wave

    const int tid = threadIdx.x;
    const int r   = tid >> 3;            // phase-a row (0..31)
    const int q   = tid & 7;             // phase-a h-block (16 contiguous h)
    const int row = blockIdx.x * RPB + r;

    // ---- stage W2 into LDS: 256 threads x 4 floats ----
    {
        const int c = tid >> 5;          // class 0..7
        const int g = tid & 31;          // float4 index 0..31
        const float4 v = *(const float4*)(W2 + c * HID + 4 * g);
        w2s[c][4 * g + 0] = v.x; w2s[c][4 * g + 1] = v.y;
        w2s[c][4 * g + 2] = v.z; w2s[c][4 * g + 3] = v.w;
    }

    // ---- cur1[h] = fmaf-chain_k( x[row,k]*W1[h,k] ) + b1[h], h=q*16+i ----
    float cur1[16];
    #pragma unroll
    for (int i = 0; i < 16; ++i) cur1[i] = 0.0f;

    const float* xrow = x + (size_t)row * IN_DIM;
    const float* w1b  = W1 + (size_t)(q * 16) * IN_DIM;
    for (int k = 0; k < IN_DIM; k += 4) {
        const float4 xv = *(const float4*)(xrow + k);
        #pragma unroll
        for (int i = 0; i < 16; ++i) {
            const float4 wv = *(const float4*)(w1b + i * IN_DIM + k);
            float c = cur1[i];
            c = fmaf(xv.x, wv.x, c);     // k ascending, single accumulator
            c = fmaf(xv.y, wv.y, c);
            c = fmaf(xv.z, wv.z, c);
            c = fmaf(xv.w, wv.w, c);
            cur1[i] = c;
        }
    }
    #pragma unroll
    for (int i = 0; i < 16; ++i)
        cur1[i] = cur1[i] + b1[q * 16 + i];

    // ---- phase-b identity: wave w -> classes {2w,2w+1}; row = lane&31 ----
    const int ln   = tid & 63;
    const int wq   = __builtin_amdgcn_readfirstlane(tid >> 6);   // 0..3
    const int cls  = 2 * wq + (ln >> 5);
    const int brow = ln & 31;
    const float b2c = b2[cls];
    const float* __restrict__ wrow = &w2s[cls][0];

    float mem1[16], spk1[16];
    #pragma unroll
    for (int i = 0; i < 16; ++i) { mem1[i] = 0.0f; spk1[i] = 0.0f; }
    float m2 = 0.0f, r2 = 0.0f, o = 0.0f;

    for (int t = 0; t < T_STEPS; ++t) {
        // phase a: layer-1 leaky update for 16 h units
        unsigned int mk = 0;
        #pragma unroll
        for (int i = 0; i < 16; ++i) {
            float tmp = 0.9f * mem1[i];   // rounded mul
            tmp = tmp + cur1[i];          // rounded add
            float m = tmp - spk1[i];      // rounded sub
            mem1[i] = m;
            const bool fire = (m > 1.0f); // == ((m-1.0f) > 0.0f) exactly
            spk1[i] = fire ? 1.0f : 0.0f;
            mk |= fire ? (1u << i) : 0u;
        }
        smask[t & 1][r * 8 + q] = (unsigned short)mk;
        __syncthreads();   // double buffer -> one barrier per timestep

        // phase b: h-ascending 128-step masked-add chain (bit-exact fma chain)
        const uint4 mv = *(const uint4*)&smask[t & 1][brow * 8];
        const unsigned int mw[4] = {mv.x, mv.y, mv.z, mv.w};
        float a = 0.0f;
        #pragma unroll
        for (int j = 0; j < 4; ++j) {
            const unsigned int m = mw[j];
            #pragma unroll
            for (int g = 0; g < 8; ++g) {             // 8 x float4 per word
                const float4 wv = *(const float4*)(wrow + j * 32 + 4 * g);
                a = a + mand(m, 4 * g + 0, wv.x);     // strict h order
                a = a + mand(m, 4 * g + 1, wv.y);
                a = a + mand(m, 4 * g + 2, wv.z);
                a = a + mand(m, 4 * g + 3, wv.w);
            }
        }
        const float c2 = a + b2c;
        float t2 = 0.9f * m2; t2 = t2 + c2; m2 = t2 - r2;
        r2 = (m2 > 1.0f) ? 1.0f : 0.0f;
        o  = o + r2;
    }

    out[(size_t)(blockIdx.x * RPB + brow) * NCLS + cls] = o;
}

extern "C" void kernel_launch(void* const* d_in, const int* in_sizes, int n_in,
                              void* d_out, int out_size, void* d_ws, size_t ws_size,
                              hipStream_t stream) {
    const float* x  = (const float*)d_in[0];
    const float* W1 = (const float*)d_in[1];
    const float* b1 = (const float*)d_in[2];
    const float* W2 = (const float*)d_in[3];
    const float* b2 = (const float*)d_in[4];
    float* out = (float*)d_out;

    const int batch = in_sizes[0] / IN_DIM;   // 16384
    const int grid  = batch / RPB;            // 512 blocks
    snn_fp32<<<grid, NTHR, 0, stream>>>(x, W1, b1, W2, b2, out);
}